// Round 11
// baseline (772.227 us; speedup 1.0000x reference)
//
#include <hip/hip_runtime.h>
#include <stdint.h>

// LocallyGroupedSelfAttention (B=512,N=200,C=512,NH=8,WS=5,HD=64).
// R4: attn one-wave-per-window (−187us). R5: un-chunk (qkv visible: 252us,
// 639 TF, 19.7M LDS conflicts, minimal 24 reads/tile but 16-way conflicted).
// R6: 4-phase + subtiled LDS: conflicts 4x down BUT 48 reads/tile (2x min)
// -> identical 630 TF. Diagnosis: LDS-read-throughput-bound both ways.
// R8: best of both: subtiled conflict-free layout + snake-ordered quadrants
// holding frags in regs (24 reads/tile = minimum) + ONE __syncthreads per
// K-tile (vmcnt drain doubles as dbuf handoff; stage issued tile-start).
// setprio dropped (m190: negative on lockstep GEMM). Epilogue/attn unchanged.
// R9/R10/R11: identical resubmits (benches failed on GPU acquisition).

typedef unsigned short u16;
typedef __bf16 bf16_t;
typedef bf16_t bf16x8 __attribute__((ext_vector_type(8)));
typedef float f32x4 __attribute__((ext_vector_type(4)));
typedef u16 u16x8 __attribute__((ext_vector_type(8)));

__device__ __forceinline__ float b2f(u16 u) {
  return __uint_as_float(((uint32_t)u) << 16);
}
__device__ __forceinline__ u16 f2b(float f) {
  uint32_t u = __float_as_uint(f);
  u += 0x7FFFu + ((u >> 16) & 1u);  // RNE
  return (u16)(u >> 16);
}

// async global -> LDS, 16 B per lane; LDS dest is wave-uniform base + lane*16.
#define GLOAD_LDS16(g, l)                                     \
  __builtin_amdgcn_global_load_lds(                           \
      (const __attribute__((address_space(1))) void*)(g),     \
      (__attribute__((address_space(3))) void*)(l), 16, 0, 0)

// Merged: flag sniff (thread 0) + bias conversion (all threads). 1 block/1024.
__global__ void k_sniff_bias(const uint32_t* __restrict__ x,
                             const void* __restrict__ qb,
                             const void* __restrict__ pb,
                             uint32_t* __restrict__ flag,
                             u16* __restrict__ bq, u16* __restrict__ bp) {
  __shared__ uint32_t fsh;
  if (threadIdx.x == 0) {
    int cnt = 0;
    for (int i = 0; i < 256; ++i) {
      uint32_t e = (x[i] >> 23) & 0xFFu;
      if (e >= 64u && e <= 192u) ++cnt;  // fp32 N(0,1) exponents land here
    }
    uint32_t fl = (cnt >= 128) ? 1u : 0u;
    *flag = fl;
    fsh = fl;
  }
  __syncthreads();
  const bool f = fsh != 0;
  for (int i = threadIdx.x; i < 2048; i += 1024) {
    if (i < 1536)
      bq[i] = f ? f2b(((const float*)qb)[i]) : ((const u16*)qb)[i];
    else {
      int j = i - 1536;
      bp[j] = f ? f2b(((const float*)pb)[j]) : ((const u16*)pb)[j];
    }
  }
}

// Merged transpose of both weights: in[512][Cc] -> out[Cc][512] bf16.
// grid (48+16, 16), block (32,8). bx<48 -> qkv (Cc=1536), else proj (Cc=512).
__global__ void k_prep_w2(const void* __restrict__ qkvw,
                          const void* __restrict__ projw,
                          u16* __restrict__ wq, u16* __restrict__ wp,
                          const uint32_t* __restrict__ flag) {
  __shared__ u16 tile[32][33];
  const bool f = (*flag) != 0;
  int bxi = blockIdx.x;
  const void* in;
  u16* out;
  int Cc;
  if (bxi < 48) {
    in = qkvw; out = wq; Cc = 1536;
  } else {
    bxi -= 48; in = projw; out = wp; Cc = 512;
  }
  const int R = 512;
  const int bx = bxi * 32, by = blockIdx.y * 32;
  const int tx = threadIdx.x, ty = threadIdx.y;
  for (int i = ty; i < 32; i += 8) {
    size_t idx = (size_t)(by + i) * Cc + bx + tx;
    tile[i][tx] = f ? f2b(((const float*)in)[idx]) : ((const u16*)in)[idx];
  }
  __syncthreads();
  for (int i = ty; i < 32; i += 8)
    out[(size_t)(bx + i) * R + by + tx] = tile[tx][i];
}

// fp32 -> bf16 chunk convert (no-op when inputs already bf16)
__global__ void k_conv_x(const float* __restrict__ x, u16* __restrict__ xb,
                         const uint32_t* __restrict__ flag, int n) {
  if ((*flag) == 0) return;
  int i = (blockIdx.x * 256 + threadIdx.x) * 8;
  if (i >= n) return;
  float4 a = *(const float4*)&x[i];
  float4 b = *(const float4*)&x[i + 4];
  u16x8 o;
  o[0] = f2b(a.x); o[1] = f2b(a.y); o[2] = f2b(a.z); o[3] = f2b(a.w);
  o[4] = f2b(b.x); o[5] = f2b(b.y); o[6] = f2b(b.z); o[7] = f2b(b.w);
  *(u16x8*)&xb[i] = o;
}

// ------------------------------------------------------------------- GEMM
// C[M][N] = A[M][K] @ Bt[N][K]^T + bias. 256x256 tile, BK=64, 8 waves 2Mx4N,
// per-wave output 128x64. Double-buffered (128KB), subtiled conflict-free
// LDS layout (R6-verified): chunk c covers u16 [c*512,(c+1)*512); a wave's
// frag reads sweep contiguous 1KB -> b128 throughput floor.
// K-tile body: stage(next) early; snake quadrants (0,0)->(0,1)->(1,1)->(1,0)
// reusing held frags: A read once per MH (16 reads), B once per NH (8) = 24
// reads/tile (the minimum). One __syncthreads per tile = dbuf handoff.
#define BM 256
#define BN 256

__global__ __launch_bounds__(512, 1) void gemm_bt_bias(
    const u16* __restrict__ A0,  // A when flag==0 (bf16 world)
    const u16* __restrict__ A1,  // A when flag==1 (pre-converted bf16)
    const u16* __restrict__ Bt, const u16* __restrict__ bias,
    void* __restrict__ Cout, const uint32_t* __restrict__ flag,
    int N, int K, int out_f32_if_flag) {
  __shared__ u16 smem[65536];  // 128 KB

  const bool f = (*flag) != 0;
  const u16* A = f ? A1 : A0;

  const int t = threadIdx.x;
  const int wave = t >> 6;         // 0..7
  const int lane = t & 63;
  const int waveM = wave >> 2;     // 0..1  -> M offset waveM*128
  const int waveN = wave & 3;      // 0..3  -> N offset waveN*64

  // T1: bijective XCD swizzle (grid sizes are multiples of 8 by construction)
  const int nbx = gridDim.x;
  const int nwg = nbx * gridDim.y;
  const int bid = blockIdx.y * nbx + blockIdx.x;
  const int cpx = nwg >> 3;
  const int swz = (bid & 7) * cpx + (bid >> 3);
  const int bm = (swz / nbx) * BM;
  const int bn = (swz % nbx) * BN;

  const int l15 = lane & 15;
  // frag ds_read lane offset (u16): cs-local 256*(lane>>5&1) + row 16*l15
  //   + 8*(lane>>4&1); + ks*512 + (rowgrp)*1024 at use site.
  const int rdOff = ((lane >> 5) & 1) * 256 + l15 * 16 + ((lane >> 4) & 1) * 8;
  // stage lane mapping: chunk c = wave*4+q covers LDS [c*512,(c+1)*512) u16;
  // lane -> row (c>>1)*16 + ((lane>>1)&15), u16 col (c&1)*32
  //   + ((lane>>5)&1)*16 + (lane&1)*8  (within the 64-wide K-tile).
  const int rowS = (lane >> 1) & 15;
  const int colS = ((lane >> 5) & 1) * 16 + (lane & 1) * 8;
  const u16* AgS[4];
  const u16* BgS[4];
#pragma unroll
  for (int q = 0; q < 4; ++q) {
    const int c = wave * 4 + q, g = c >> 1, p = c & 1;
    AgS[q] = &A[(size_t)(bm + g * 16 + rowS) * K + p * 32 + colS];
    BgS[q] = &Bt[(size_t)(bn + g * 16 + rowS) * K + p * 32 + colS];
  }

  f32x4 acc[8][4] = {};
  const int NT = K / 64;  // 8

#define STAGE_OP(PTRS, dstU16, kN)                                          \
  {                                                                         \
    _Pragma("unroll") for (int q = 0; q < 4; ++q)                           \
        GLOAD_LDS16(PTRS[q] + (kN), &smem[(dstU16) + (wave * 4 + q) * 512]); \
  }

  // prologue: stage tile 0 into buf0, drain.
  STAGE_OP(AgS, 0, 0);
  STAGE_OP(BgS, 16384, 0);
  __syncthreads();

  for (int tt = 0; tt < NT; ++tt) {
    const int ab = (tt & 1) * 32768;  // current buf A base (u16)
    const int bb = ab + 16384;        // current buf B base
    if (tt + 1 < NT) {                // issue next-tile staging early
      const int sab = ((tt + 1) & 1) * 32768;
      const int kN = (tt + 1) * 64;
      STAGE_OP(AgS, sab, kN);
      STAGE_OP(BgS, sab + 16384, kN);
    }
    bf16x8 a0[4][2], a1[4][2], b0[2][2], b1[2][2];
    // ---- quadrant (0,0): read A(MH0), B(NH0)
#pragma unroll
    for (int ii = 0; ii < 4; ++ii)
#pragma unroll
      for (int ks = 0; ks < 2; ++ks)
        a0[ii][ks] = *(const bf16x8*)&smem[ab + (waveM * 8 + ii) * 1024 +
                                           ks * 512 + rdOff];
#pragma unroll
    for (int jj = 0; jj < 2; ++jj)
#pragma unroll
      for (int ks = 0; ks < 2; ++ks)
        b0[jj][ks] = *(const bf16x8*)&smem[bb + (waveN * 4 + jj) * 1024 +
                                           ks * 512 + rdOff];
#pragma unroll
    for (int ii = 0; ii < 4; ++ii)
#pragma unroll
      for (int jj = 0; jj < 2; ++jj)
#pragma unroll
        for (int ks = 0; ks < 2; ++ks)
          acc[ii][jj] = __builtin_amdgcn_mfma_f32_16x16x32_bf16(
              a0[ii][ks], b0[jj][ks], acc[ii][jj], 0, 0, 0);
    // ---- quadrant (0,1): read B(NH1), reuse a0
#pragma unroll
    for (int jj = 0; jj < 2; ++jj)
#pragma unroll
      for (int ks = 0; ks < 2; ++ks)
        b1[jj][ks] = *(const bf16x8*)&smem[bb + (waveN * 4 + 2 + jj) * 1024 +
                                           ks * 512 + rdOff];
#pragma unroll
    for (int ii = 0; ii < 4; ++ii)
#pragma unroll
      for (int jj = 0; jj < 2; ++jj)
#pragma unroll
        for (int ks = 0; ks < 2; ++ks)
          acc[ii][2 + jj] = __builtin_amdgcn_mfma_f32_16x16x32_bf16(
              a0[ii][ks], b1[jj][ks], acc[ii][2 + jj], 0, 0, 0);
    // ---- quadrant (1,1): read A(MH1), reuse b1
#pragma unroll
    for (int ii = 0; ii < 4; ++ii)
#pragma unroll
      for (int ks = 0; ks < 2; ++ks)
        a1[ii][ks] = *(const bf16x8*)&smem[ab + (waveM * 8 + 4 + ii) * 1024 +
                                           ks * 512 + rdOff];
#pragma unroll
    for (int ii = 0; ii < 4; ++ii)
#pragma unroll
      for (int jj = 0; jj < 2; ++jj)
#pragma unroll
        for (int ks = 0; ks < 2; ++ks)
          acc[4 + ii][2 + jj] = __builtin_amdgcn_mfma_f32_16x16x32_bf16(
              a1[ii][ks], b1[jj][ks], acc[4 + ii][2 + jj], 0, 0, 0);
    // ---- quadrant (1,0): reuse a1, b0 (no reads)
#pragma unroll
    for (int ii = 0; ii < 4; ++ii)
#pragma unroll
      for (int jj = 0; jj < 2; ++jj)
#pragma unroll
        for (int ks = 0; ks < 2; ++ks)
          acc[4 + ii][jj] = __builtin_amdgcn_mfma_f32_16x16x32_bf16(
              a1[ii][ks], b0[jj][ks], acc[4 + ii][jj], 0, 0, 0);
    // dbuf handoff: drains vmcnt (next tile resident) + all reads consumed.
    __syncthreads();
  }
#undef STAGE_OP

  float biasf[4];
#pragma unroll
  for (int j = 0; j < 4; ++j)
    biasf[j] = b2f(bias[bn + waveN * 64 + j * 16 + l15]);

  // C/D frag: col = lane&15, row = (lane>>4)*4 + reg  [m89/m91]
  if (out_f32_if_flag && f) {
    float* C = (float*)Cout;
#pragma unroll
    for (int i = 0; i < 8; ++i) {
      const int row0 = waveM * 128 + i * 16 + (lane >> 4) * 4;
#pragma unroll
      for (int j = 0; j < 4; ++j) {
        const int col = waveN * 64 + j * 16 + l15;
#pragma unroll
        for (int r = 0; r < 4; ++r)
          C[(size_t)(bm + row0 + r) * N + bn + col] = acc[i][j][r] + biasf[j];
      }
    }
  } else {
    // bf16 out: repack 128 rows at a time through LDS (64 KB = 128x256 u16)
    u16* C = (u16*)Cout;
#pragma unroll
    for (int h = 0; h < 2; ++h) {
      if (waveM == h) {
#pragma unroll
        for (int i = 0; i < 8; ++i) {
          const int row0 = i * 16 + (lane >> 4) * 4;  // 0..127
#pragma unroll
          for (int j = 0; j < 4; ++j) {
            const int col = waveN * 64 + j * 16 + l15;
#pragma unroll
            for (int r = 0; r < 4; ++r)
              smem[(row0 + r) * 256 + col] = f2b(acc[i][j][r] + biasf[j]);
          }
        }
      }
      __syncthreads();
#pragma unroll
      for (int s = 0; s < 8; ++s) {
        const int vi = s * 512 + t;
        const int row = vi >> 5;           // 0..127
        const int col = (vi & 31) * 8;     // 0..248
        u16x8 v = *(const u16x8*)&smem[row * 256 + col];
        *(u16x8*)&C[(size_t)(bm + h * 128 + row) * N + bn + col] = v;
      }
      __syncthreads();
    }
  }
}

// ------------------------------------------------------------- attention
// qkv[rows][1536]: Q [0,512), K [512,1024), V [1024,1536); head h at h*64.
// One wave per WINDOW. lane = h*8 + dg: head h = lane>>3, d-elems
// dg*8..dg*8+7. Dot over d=64 = 8 local FMA + 3-level butterfly within the
// 8-lane d-group. All loads/stores u16x8 (16 B/lane, coalesced 1 KB rows).
__global__ __launch_bounds__(256) void attn_win(const u16* __restrict__ qkv,
                                                u16* __restrict__ o,
                                                int nwin) {
  const int w = blockIdx.x * 4 + (threadIdx.x >> 6);
  if (w >= nwin) return;
  const int lane = threadIdx.x & 63;
  const int h = lane >> 3;        // head 0..7
  const int d0 = (lane & 7) * 8;  // d-group base 0..56
  const u16* base = qkv + (size_t)w * (5 * 1536) + h * 64 + d0;

  float qf[5][8], kf[5][8], vf[5][8];
#pragma unroll
  for (int i = 0; i < 5; ++i) {
    u16x8 vq = *(const u16x8*)&base[i * 1536];
    u16x8 vk = *(const u16x8*)&base[i * 1536 + 512];
    u16x8 vv = *(const u16x8*)&base[i * 1536 + 1024];
#pragma unroll
    for (int e = 0; e < 8; ++e) {
      qf[i][e] = b2f(vq[e]);
      kf[i][e] = b2f(vk[e]);
      vf[i][e] = b2f(vv[e]);
    }
  }

  // partial scores over this lane's 8 d-elems
  float s[5][5];
#pragma unroll
  for (int i = 0; i < 5; ++i)
#pragma unroll
    for (int j = 0; j < 5; ++j) {
      float acc = 0.f;
#pragma unroll
      for (int e = 0; e < 8; ++e) acc += qf[i][e] * kf[j][e];
      s[i][j] = acc;
    }
  // butterfly within 8-lane d-group (lane bits 0-2): full dot over d=64
#pragma unroll
  for (int off = 1; off < 8; off <<= 1) {
#pragma unroll
    for (int i = 0; i < 5; ++i)
#pragma unroll
      for (int j = 0; j < 5; ++j) s[i][j] += __shfl_xor(s[i][j], off, 64);
  }

  const float SCALE = 0.125f;  // 64^-0.5
  u16* ob = o + (size_t)w * (5 * 512) + h * 64 + d0;
#pragma unroll
  for (int i = 0; i < 5; ++i) {
    float m = s[i][0];
#pragma unroll
    for (int j = 1; j < 5; ++j) m = fmaxf(m, s[i][j]);
    float e0[5], l = 0.f;
#pragma unroll
    for (int j = 0; j < 5; ++j) {
      e0[j] = __expf((s[i][j] - m) * SCALE);
      l += e0[j];
    }
    const float rl = 1.f / l;
    u16x8 out;
#pragma unroll
    for (int e = 0; e < 8; ++e) {
      float acc = 0.f;
#pragma unroll
      for (int j = 0; j < 5; ++j) acc += e0[j] * vf[j][e];
      out[e] = f2b(acc * rl);
    }
    *(u16x8*)&ob[i * 512] = out;
  }
}

// ---------------------------------------------------------------- launch
extern "C" void kernel_launch(void* const* d_in, const int* in_sizes, int n_in,
                              void* d_out, int out_size, void* d_ws,
                              size_t ws_size, hipStream_t stream) {
  const void* x      = d_in[0];  // [102400][512]  fp32 or bf16
  const void* qkv_w  = d_in[1];  // [512][1536]
  const void* qkv_b  = d_in[2];  // [1536]
  const void* proj_w = d_in[3];  // [512][512]
  const void* proj_b = d_in[4];  // [512]

  const int M = 102400, K = 512, N1 = 1536, N2 = 512;

  // Dynamic chunking: CH=1 needs ~527 MB of ws; fall back if less.
  const size_t fixed = 8192 + 1572864 + 524288 + (size_t)M * 512 * 2;
  int CH = 4;
  if (ws_size >= fixed + (size_t)M * 2048 * 2) CH = 1;
  else if (ws_size >= fixed + (size_t)(M / 2) * 2048 * 2) CH = 2;
  const int MC = M / CH;

  char* ws = (char*)d_ws;
  uint32_t* flag = (uint32_t*)ws;                       // @0
  u16* bq      = (u16*)(ws + 256);                      // 1536*2
  u16* bp      = (u16*)(ws + 256 + 3072);               // 512*2
  u16* wt_qkv  = (u16*)(ws + 8192);                     // 1536*512*2
  u16* wt_proj = (u16*)(ws + 8192 + 1572864);           // 512*512*2
  u16* attnb   = (u16*)(ws + 8192 + 1572864 + 524288);  // M*512*2 = 104.9 MB
  u16* qkvc    = (u16*)((char*)attnb + (size_t)M * 512 * 2);   // MC*1536*2
  u16* xbc     = (u16*)((char*)qkvc + (size_t)MC * 1536 * 2);  // MC*512*2

  k_sniff_bias<<<1, 1024, 0, stream>>>((const uint32_t*)x, qkv_b, proj_b, flag,
                                       bq, bp);
  k_prep_w2<<<dim3(64, 16), dim3(32, 8), 0, stream>>>(qkv_w, proj_w, wt_qkv,
                                                      wt_proj, flag);
  for (int c = 0; c < CH; ++c) {
    const size_t roff = (size_t)c * MC * 512;
    k_conv_x<<<MC * 512 / 2048, 256, 0, stream>>>((const float*)x + roff, xbc,
                                                  flag, MC * 512);
    // qkv grid: (1536/256) x (MC/256); CH=1 -> 6x400=2400 blocks (%8==0)
    gemm_bt_bias<<<dim3(N1 / BN, MC / BM), 512, 0, stream>>>(
        (const u16*)x + roff, xbc, wt_qkv, bq, qkvc, flag, N1, K, 0);
    // one wave per window: MC/5 windows, 4 waves/block
    attn_win<<<(MC / 5) / 4, 256, 0, stream>>>(qkvc, (u16*)attnb + roff,
                                               MC / 5);
  }
  // proj grid 2 x 400 = 800 blocks (%8==0)
  gemm_bt_bias<<<dim3(N2 / BN, M / BM), 512, 0, stream>>>(
      attnb, attnb, wt_proj, bp, d_out, flag, N2, K, 1);
}